// Round 1
// baseline (1137.387 us; speedup 1.0000x reference)
//
#include <hip/hip_runtime.h>
#include <math.h>

// Problem constants (ProbAttention: B=4, L=4096, H=8, D=64, S=U=ceil(ln L)=9)
#define B_ 4
#define L_ 4096
#define H_ 8
#define D_ 64
#define S_ 9
#define U_ 9

// ---------------------------------------------------------------------------
// Kernel 1: M[b,h,l] = max_s(Q[b,h,l]·K[b,h,idx[l,s]]) - sum_s(...)/L
// One thread per (b,h,l). Q row held in 16 float4 regs; K rows streamed.
// ---------------------------------------------------------------------------
__global__ void kernel_M(const float* __restrict__ Q, const float* __restrict__ K,
                         const int* __restrict__ idx, float* __restrict__ M) {
    int t = blockIdx.x * blockDim.x + threadIdx.x;   // t = (b*H+h)*L + l
    int l  = t & (L_ - 1);
    int bh = t >> 12;           // L = 4096 = 2^12
    int h  = bh & (H_ - 1);
    int b  = bh >> 3;

    const float4* qrow = (const float4*)(Q + (size_t)((b * L_ + l) * H_ + h) * D_);
    float4 q[16];
#pragma unroll
    for (int c = 0; c < 16; ++c) q[c] = qrow[c];

    float mx = -INFINITY, sm = 0.0f;
#pragma unroll
    for (int s = 0; s < S_; ++s) {
        int ki = idx[l * S_ + s];
        const float4* krow = (const float4*)(K + (size_t)((b * L_ + ki) * H_ + h) * D_);
        float acc = 0.0f;
#pragma unroll
        for (int c = 0; c < 16; ++c) {
            float4 kv = krow[c];
            acc += q[c].x * kv.x + q[c].y * kv.y + q[c].z * kv.z + q[c].w * kv.w;
        }
        mx = fmaxf(mx, acc);
        sm += acc;
    }
    M[t] = mx - sm * (1.0f / (float)L_);
}

// ---------------------------------------------------------------------------
// Kernel 2: top-9 indices of M per (b,h). 32 blocks. Iterative argmax with
// tie-break (value desc, index asc) — matches jax.lax.top_k stable order.
// ---------------------------------------------------------------------------
__global__ void kernel_topk(const float* __restrict__ M, int* __restrict__ Mtop) {
    int bh = blockIdx.x;
    __shared__ float vals[L_];
    __shared__ float rv[256];
    __shared__ int   ri[256];
    const float* Ms = M + (size_t)bh * L_;
    for (int i = threadIdx.x; i < L_; i += 256) vals[i] = Ms[i];
    __syncthreads();

    for (int it = 0; it < U_; ++it) {
        float bv = -INFINITY;
        int   bi = 0x7fffffff;
        for (int i = threadIdx.x; i < L_; i += 256) {
            float v = vals[i];
            if (v > bv || (v == bv && i < bi)) { bv = v; bi = i; }
        }
        rv[threadIdx.x] = bv; ri[threadIdx.x] = bi;
        __syncthreads();
        for (int off = 128; off > 0; off >>= 1) {
            if (threadIdx.x < off) {
                float v2 = rv[threadIdx.x + off];
                int   i2 = ri[threadIdx.x + off];
                if (v2 > rv[threadIdx.x] ||
                    (v2 == rv[threadIdx.x] && i2 < ri[threadIdx.x])) {
                    rv[threadIdx.x] = v2; ri[threadIdx.x] = i2;
                }
            }
            __syncthreads();
        }
        if (threadIdx.x == 0) {
            Mtop[bh * U_ + it] = ri[0];
            vals[ri[0]] = -INFINITY;
        }
        __syncthreads();
    }
}

// ---------------------------------------------------------------------------
// Kernel 3: vmean[b,h,d] = mean_l V[b,l,h,d]. 32 blocks, thread=(d, g).
// ---------------------------------------------------------------------------
__global__ void kernel_vmean(const float* __restrict__ V, float* __restrict__ vmean) {
    int bh = blockIdx.x;
    int h = bh & (H_ - 1), b = bh >> 3;
    int d = threadIdx.x & 63, g = threadIdx.x >> 6;
    float s = 0.0f;
    for (int l = g; l < L_; l += 4)
        s += V[(size_t)((b * L_ + l) * H_ + h) * D_ + d];
    __shared__ float red[4][64];
    red[g][d] = s;
    __syncthreads();
    if (g == 0)
        vmean[bh * D_ + d] =
            (red[0][d] + red[1][d] + red[2][d] + red[3][d]) * (1.0f / (float)L_);
}

// ---------------------------------------------------------------------------
// Kernel 4: fill context output (B,L,H,D) with vmean broadcast. float4 writes.
// ---------------------------------------------------------------------------
__global__ void kernel_fill(float* __restrict__ out, const float* __restrict__ vmean) {
    int i = blockIdx.x * blockDim.x + threadIdx.x;   // float4 index, 2097152 total
    int d4 = i & 15;
    int h  = (i >> 4) & (H_ - 1);
    int b  = i >> (4 + 3 + 12);                      // skip d4(4b), h(3b), l(12b)
    ((float4*)out)[i] = ((const float4*)vmean)[(b * H_ + h) * 16 + d4];
}

// ---------------------------------------------------------------------------
// Kernel 5: one block per (b,h,u): scores row (1x4096), softmax, write attn.
// Scores stay in registers (16/thread); two LDS reductions (max, sum).
// ---------------------------------------------------------------------------
__global__ void kernel_scores(const float* __restrict__ Q, const float* __restrict__ K,
                              const int* __restrict__ Mtop, float* __restrict__ attn) {
    int blk = blockIdx.x;           // bh*U + u
    int u = blk % U_, bh = blk / U_;
    int h = bh & (H_ - 1), b = bh >> 3;
    int l = Mtop[bh * U_ + u];

    __shared__ float qs[D_];
    if (threadIdx.x < D_)
        qs[threadIdx.x] = Q[(size_t)((b * L_ + l) * H_ + h) * D_ + threadIdx.x];
    __syncthreads();

    float4 qv[16];
#pragma unroll
    for (int c = 0; c < 16; ++c) qv[c] = ((const float4*)qs)[c];

    float s[16];
    float mx = -INFINITY;
#pragma unroll
    for (int i = 0; i < 16; ++i) {
        int k = threadIdx.x + 256 * i;
        const float4* krow = (const float4*)(K + (size_t)((b * L_ + k) * H_ + h) * D_);
        float acc = 0.0f;
#pragma unroll
        for (int c = 0; c < 16; ++c) {
            float4 kv = krow[c];
            acc += qv[c].x * kv.x + qv[c].y * kv.y + qv[c].z * kv.z + qv[c].w * kv.w;
        }
        s[i] = acc * 0.125f;        // 1/sqrt(64)
        mx = fmaxf(mx, s[i]);
    }

    __shared__ float red[256];
    __shared__ float bmax, bsum;
    red[threadIdx.x] = mx;
    __syncthreads();
    for (int off = 128; off > 0; off >>= 1) {
        if (threadIdx.x < off)
            red[threadIdx.x] = fmaxf(red[threadIdx.x], red[threadIdx.x + off]);
        __syncthreads();
    }
    if (threadIdx.x == 0) bmax = red[0];
    __syncthreads();

    float sum = 0.0f;
#pragma unroll
    for (int i = 0; i < 16; ++i) {
        s[i] = expf(s[i] - bmax);
        sum += s[i];
    }
    red[threadIdx.x] = sum;
    __syncthreads();
    for (int off = 128; off > 0; off >>= 1) {
        if (threadIdx.x < off)
            red[threadIdx.x] += red[threadIdx.x + off];
        __syncthreads();
    }
    if (threadIdx.x == 0) bsum = red[0];
    __syncthreads();

    float inv = 1.0f / bsum;
    float* arow = attn + (size_t)blk * L_;
#pragma unroll
    for (int i = 0; i < 16; ++i)
        arow[threadIdx.x + 256 * i] = s[i] * inv;
}

// ---------------------------------------------------------------------------
// Kernel 6: ctx_top row = attn_row @ V, scattered into context at l=Mtop.
// One block per (b,h,u); thread = (d, g). attn read wave-uniform, V coalesced.
// ---------------------------------------------------------------------------
__global__ void kernel_ctx(const float* __restrict__ attn, const float* __restrict__ V,
                           const int* __restrict__ Mtop, float* __restrict__ out) {
    int blk = blockIdx.x;
    int u = blk % U_, bh = blk / U_;
    int h = bh & (H_ - 1), b = bh >> 3;
    const float* arow = attn + (size_t)blk * L_;
    int d = threadIdx.x & 63, g = threadIdx.x >> 6;
    float acc = 0.0f;
    for (int k = g; k < L_; k += 4)
        acc += arow[k] * V[(size_t)((b * L_ + k) * H_ + h) * D_ + d];
    __shared__ float red[4][64];
    red[g][d] = acc;
    __syncthreads();
    if (g == 0) {
        int l = Mtop[bh * U_ + u];
        out[(size_t)((b * L_ + l) * H_ + h) * D_ + d] =
            red[0][d] + red[1][d] + red[2][d] + red[3][d];
    }
}

extern "C" void kernel_launch(void* const* d_in, const int* in_sizes, int n_in,
                              void* d_out, int out_size, void* d_ws, size_t ws_size,
                              hipStream_t stream) {
    const float* Q   = (const float*)d_in[0];
    const float* K   = (const float*)d_in[1];
    const float* V   = (const float*)d_in[2];
    const int*   idx = (const int*)d_in[3];

    float* ctx_out  = (float*)d_out;                               // B*L*H*D
    float* attn_out = (float*)d_out + (size_t)B_ * L_ * H_ * D_;   // B*H*U*L

    // workspace layout
    float* M     = (float*)d_ws;                                   // B*H*L floats
    float* vmean = M + (size_t)B_ * H_ * L_;                       // B*H*D floats
    int*   Mtop  = (int*)(vmean + B_ * H_ * D_);                   // B*H*U ints

    kernel_M<<<(B_ * H_ * L_) / 256, 256, 0, stream>>>(Q, K, idx, M);
    kernel_topk<<<B_ * H_, 256, 0, stream>>>(M, Mtop);
    kernel_vmean<<<B_ * H_, 256, 0, stream>>>(V, vmean);
    kernel_fill<<<(B_ * L_ * H_ * D_ / 4) / 256, 256, 0, stream>>>(ctx_out, vmean);
    kernel_scores<<<B_ * H_ * U_, 256, 0, stream>>>(Q, K, Mtop, attn_out);
    kernel_ctx<<<B_ * H_ * U_, 256, 0, stream>>>(attn_out, V, Mtop, ctx_out);
}

// Round 2
// 482.506 us; speedup vs baseline: 2.3573x; 2.3573x over previous
//
#include <hip/hip_runtime.h>
#include <math.h>

// Problem constants (ProbAttention: B=4, L=4096, H=8, D=64, S=U=ceil(ln L)=9)
#define B_ 4
#define L_ 4096
#define H_ 8
#define D_ 64
#define S_ 9
#define U_ 9
#define VC_ 64   // vmean stage-1 chunks per batch (chunk = L/VC = 64 rows)
#define CC_ 8    // ctx stage-1 chunks per row   (chunk = L/CC = 512 keys)

// ---------------------------------------------------------------------------
// Kernel 1: M[b,h,l] = max_s(Q[b,h,l]·K[b,h,idx[l,s]]) - sum_s(...)/L
// One thread per (b,h,l). Q row held in 16 float4 regs; K rows gathered (L2).
// ---------------------------------------------------------------------------
__global__ void kernel_M(const float* __restrict__ Q, const float* __restrict__ K,
                         const int* __restrict__ idx, float* __restrict__ M) {
    int t = blockIdx.x * blockDim.x + threadIdx.x;   // t = (b*H+h)*L + l
    int l  = t & (L_ - 1);
    int bh = t >> 12;           // L = 4096 = 2^12
    int h  = bh & (H_ - 1);
    int b  = bh >> 3;

    const float4* qrow = (const float4*)(Q + (size_t)((b * L_ + l) * H_ + h) * D_);
    float4 q[16];
#pragma unroll
    for (int c = 0; c < 16; ++c) q[c] = qrow[c];

    int ki[S_];
#pragma unroll
    for (int s = 0; s < S_; ++s) ki[s] = idx[l * S_ + s];

    float mx = -INFINITY, sm = 0.0f;
#pragma unroll
    for (int s = 0; s < S_; ++s) {
        const float4* krow = (const float4*)(K + (size_t)((b * L_ + ki[s]) * H_ + h) * D_);
        float acc = 0.0f;
#pragma unroll
        for (int c = 0; c < 16; ++c) {
            float4 kv = krow[c];
            acc += q[c].x * kv.x + q[c].y * kv.y + q[c].z * kv.z + q[c].w * kv.w;
        }
        mx = fmaxf(mx, acc);
        sm += acc;
    }
    M[t] = mx - sm * (1.0f / (float)L_);
}

// ---------------------------------------------------------------------------
// Kernel 2: top-9 indices of M per (b,h). 32 blocks. Iterative argmax with
// tie-break (value desc, index asc) — matches jax.lax.top_k stable order.
// ---------------------------------------------------------------------------
__global__ void kernel_topk(const float* __restrict__ M, int* __restrict__ Mtop) {
    int bh = blockIdx.x;
    __shared__ float vals[L_];
    __shared__ float rv[256];
    __shared__ int   ri[256];
    const float* Ms = M + (size_t)bh * L_;
    for (int i = threadIdx.x; i < L_; i += 256) vals[i] = Ms[i];
    __syncthreads();

    for (int it = 0; it < U_; ++it) {
        float bv = -INFINITY;
        int   bi = 0x7fffffff;
        for (int i = threadIdx.x; i < L_; i += 256) {
            float v = vals[i];
            if (v > bv || (v == bv && i < bi)) { bv = v; bi = i; }
        }
        rv[threadIdx.x] = bv; ri[threadIdx.x] = bi;
        __syncthreads();
        for (int off = 128; off > 0; off >>= 1) {
            if (threadIdx.x < off) {
                float v2 = rv[threadIdx.x + off];
                int   i2 = ri[threadIdx.x + off];
                if (v2 > rv[threadIdx.x] ||
                    (v2 == rv[threadIdx.x] && i2 < ri[threadIdx.x])) {
                    rv[threadIdx.x] = v2; ri[threadIdx.x] = i2;
                }
            }
            __syncthreads();
        }
        if (threadIdx.x == 0) {
            Mtop[bh * U_ + it] = ri[0];
            vals[ri[0]] = -INFINITY;
        }
        __syncthreads();
    }
}

// ---------------------------------------------------------------------------
// Kernel 3a: vmean partials. grid = B*VC_ blocks, 256 threads, fully
// coalesced float4 loads over the contiguous (l, h, d) layout.
// vpart[(b*VC_+c)*512 + j] = sum over chunk of V[b, l, j/64, j%64]
// ---------------------------------------------------------------------------
__global__ void kernel_vmean1(const float* __restrict__ V, float* __restrict__ vpart) {
    int blk = blockIdx.x;
    int c = blk & (VC_ - 1), b = blk >> 6;          // VC_ = 64
    int col = threadIdx.x & 127;                    // float4 col within 2048B row
    int lp  = threadIdx.x >> 7;                     // 0/1
    const int CHUNK = L_ / VC_;                     // 64
    const float4* base = (const float4*)(V + (size_t)b * L_ * H_ * D_);
    float4 acc = make_float4(0.f, 0.f, 0.f, 0.f);
    for (int l = c * CHUNK + lp; l < (c + 1) * CHUNK; l += 2) {
        float4 v = base[(size_t)l * 128 + col];
        acc.x += v.x; acc.y += v.y; acc.z += v.z; acc.w += v.w;
    }
    __shared__ float4 red[256];
    red[threadIdx.x] = acc;
    __syncthreads();
    if (lp == 0) {
        float4 o = red[threadIdx.x + 128];
        acc.x += o.x; acc.y += o.y; acc.z += o.z; acc.w += o.w;
        ((float4*)vpart)[(size_t)blk * 128 + col] = acc;
    }
}

// Kernel 3b: combine partials. grid = B*H (32), 64 threads.
__global__ void kernel_vmean2(const float* __restrict__ vpart, float* __restrict__ vmean) {
    int bh = blockIdx.x;
    int h = bh & (H_ - 1), b = bh >> 3;
    int d = threadIdx.x;
    float s = 0.0f;
    for (int c = 0; c < VC_; ++c)
        s += vpart[(size_t)(b * VC_ + c) * (H_ * D_) + h * D_ + d];
    vmean[bh * D_ + d] = s * (1.0f / (float)L_);
}

// ---------------------------------------------------------------------------
// Kernel 4: fill context output (B,L,H,D) with vmean broadcast. float4 writes.
// ---------------------------------------------------------------------------
__global__ void kernel_fill(float* __restrict__ out, const float* __restrict__ vmean) {
    int i = blockIdx.x * blockDim.x + threadIdx.x;   // float4 index, 2097152 total
    int d4 = i & 15;
    int h  = (i >> 4) & (H_ - 1);
    int b  = i >> (4 + 3 + 12);                      // skip d4(4b), h(3b), l(12b)
    ((float4*)out)[i] = ((const float4*)vmean)[(b * H_ + h) * 16 + d4];
}

// ---------------------------------------------------------------------------
// Kernel 5: one block (1024 thr) per (b,h,u): scores row (1x4096), softmax,
// write attn. 4 scores/thread; two LDS reductions (max, sum).
// ---------------------------------------------------------------------------
__global__ void kernel_scores(const float* __restrict__ Q, const float* __restrict__ K,
                              const int* __restrict__ Mtop, float* __restrict__ attn) {
    int blk = blockIdx.x;           // bh*U + u
    int u = blk % U_, bh = blk / U_;
    int h = bh & (H_ - 1), b = bh >> 3;
    int l = Mtop[bh * U_ + u];

    __shared__ float qs[D_];
    if (threadIdx.x < D_)
        qs[threadIdx.x] = Q[(size_t)((b * L_ + l) * H_ + h) * D_ + threadIdx.x];
    __syncthreads();

    float4 qv[16];
#pragma unroll
    for (int c = 0; c < 16; ++c) qv[c] = ((const float4*)qs)[c];

    float s[4];
    float mx = -INFINITY;
#pragma unroll
    for (int i = 0; i < 4; ++i) {
        int k = threadIdx.x + 1024 * i;
        const float4* krow = (const float4*)(K + (size_t)((b * L_ + k) * H_ + h) * D_);
        float acc = 0.0f;
#pragma unroll
        for (int c = 0; c < 16; ++c) {
            float4 kv = krow[c];
            acc += qv[c].x * kv.x + qv[c].y * kv.y + qv[c].z * kv.z + qv[c].w * kv.w;
        }
        s[i] = acc * 0.125f;        // 1/sqrt(64)
        mx = fmaxf(mx, s[i]);
    }

    __shared__ float red[1024];
    __shared__ float bmax, bsum;
    red[threadIdx.x] = mx;
    __syncthreads();
    for (int off = 512; off > 0; off >>= 1) {
        if (threadIdx.x < off)
            red[threadIdx.x] = fmaxf(red[threadIdx.x], red[threadIdx.x + off]);
        __syncthreads();
    }
    if (threadIdx.x == 0) bmax = red[0];
    __syncthreads();

    float sum = 0.0f;
#pragma unroll
    for (int i = 0; i < 4; ++i) {
        s[i] = expf(s[i] - bmax);
        sum += s[i];
    }
    red[threadIdx.x] = sum;
    __syncthreads();
    for (int off = 512; off > 0; off >>= 1) {
        if (threadIdx.x < off)
            red[threadIdx.x] += red[threadIdx.x + off];
        __syncthreads();
    }
    if (threadIdx.x == 0) bsum = red[0];
    __syncthreads();

    float inv = 1.0f / bsum;
    float* arow = attn + (size_t)blk * L_;
#pragma unroll
    for (int i = 0; i < 4; ++i)
        arow[threadIdx.x + 1024 * i] = s[i] * inv;
}

// ---------------------------------------------------------------------------
// Kernel 6a: ctx partials. grid = (B*H*U)*CC_ blocks, 1024 threads.
// Thread (d = t&63, g = t>>6): 32-iteration k loop over the 512-key chunk.
// ---------------------------------------------------------------------------
__global__ void kernel_ctx1(const float* __restrict__ attn, const float* __restrict__ V,
                            float* __restrict__ cpart) {
    int blk = blockIdx.x;
    int c   = blk & (CC_ - 1);         // CC_ = 8
    int row = blk >> 3;                // bh*U + u
    int bh  = row / U_;
    int h = bh & (H_ - 1), b = bh >> 3;
    const float* arow = attn + (size_t)row * L_;
    int d = threadIdx.x & 63, g = threadIdx.x >> 6;   // g in 0..15
    int k0 = c * (L_ / CC_);
    float acc = 0.0f;
    for (int i = 0; i < 32; ++i) {
        int k = k0 + g + 16 * i;
        acc += arow[k] * V[(size_t)((b * L_ + k) * H_ + h) * D_ + d];
    }
    __shared__ float red[16][64];
    red[g][d] = acc;
    __syncthreads();
    for (int off = 8; off > 0; off >>= 1) {
        if (g < off) red[g][d] += red[g + off][d];
        __syncthreads();
    }
    if (g == 0) cpart[(size_t)blk * 64 + d] = red[0][d];
}

// Kernel 6b: combine + scatter. grid = B*H*U (288), 64 threads.
__global__ void kernel_ctx2(const float* __restrict__ cpart, const int* __restrict__ Mtop,
                            float* __restrict__ out) {
    int row = blockIdx.x;
    int u = row % U_, bh = row / U_;
    int h = bh & (H_ - 1), b = bh >> 3;
    int d = threadIdx.x;
    float s = 0.0f;
#pragma unroll
    for (int c = 0; c < CC_; ++c)
        s += cpart[(size_t)(row * CC_ + c) * 64 + d];
    int l = Mtop[bh * U_ + u];
    out[(size_t)((b * L_ + l) * H_ + h) * D_ + d] = s;
}

extern "C" void kernel_launch(void* const* d_in, const int* in_sizes, int n_in,
                              void* d_out, int out_size, void* d_ws, size_t ws_size,
                              hipStream_t stream) {
    const float* Q   = (const float*)d_in[0];
    const float* K   = (const float*)d_in[1];
    const float* V   = (const float*)d_in[2];
    const int*   idx = (const int*)d_in[3];

    float* ctx_out  = (float*)d_out;                               // B*L*H*D
    float* attn_out = (float*)d_out + (size_t)B_ * L_ * H_ * D_;   // B*H*U*L

    // workspace layout (floats): M | vpart | vmean | cpart | Mtop
    float* M     = (float*)d_ws;                                   // B*H*L      = 131072
    float* vpart = M + (size_t)B_ * H_ * L_;                       // B*VC*H*D   = 131072
    float* vmean = vpart + (size_t)B_ * VC_ * H_ * D_;             // B*H*D      = 2048
    float* cpart = vmean + B_ * H_ * D_;                           // 288*CC*64  = 147456
    int*   Mtop  = (int*)(cpart + (size_t)B_ * H_ * U_ * CC_ * 64);// 288 ints

    kernel_M<<<(B_ * H_ * L_) / 256, 256, 0, stream>>>(Q, K, idx, M);
    kernel_topk<<<B_ * H_, 256, 0, stream>>>(M, Mtop);
    kernel_vmean1<<<B_ * VC_, 256, 0, stream>>>(V, vpart);
    kernel_vmean2<<<B_ * H_, 64, 0, stream>>>(vpart, vmean);
    kernel_fill<<<(B_ * L_ * H_ * D_ / 4) / 256, 256, 0, stream>>>(ctx_out, vmean);
    kernel_scores<<<B_ * H_ * U_, 1024, 0, stream>>>(Q, K, Mtop, attn_out);
    kernel_ctx1<<<B_ * H_ * U_ * CC_, 1024, 0, stream>>>(attn_out, V, cpart);
    kernel_ctx2<<<B_ * H_ * U_, 64, 0, stream>>>(cpart, Mtop, ctx_out);
}

// Round 3
// 302.026 us; speedup vs baseline: 3.7659x; 1.5976x over previous
//
#include <hip/hip_runtime.h>
#include <math.h>

// Problem constants (ProbAttention: B=4, L=4096, H=8, D=64, S=U=ceil(ln L)=9)
#define B_ 4
#define L_ 4096
#define H_ 8
#define D_ 64
#define S_ 9
#define U_ 9
#define VC_ 64   // vmean stage-1 chunks per batch (chunk = L/VC = 64 rows)
#define CC_ 8    // ctx stage-1 chunks per row   (chunk = L/CC = 512 keys)
#define TKC_ 8   // topk stage-1 chunks per (b,h) (chunk = 512 elems)

// ---------------------------------------------------------------------------
// Kernel 1: M[b,h,l] = max_s(Q[b,h,l]·K[b,h,idx[l,s]]) - sum_s(...)/L
// 4 lanes per (l,s) dot. Block = 576 thr (9 waves: wave w == sample s,
// 16 l's per wave). Grid = 32 bh * 256 chunks, XCD-swizzled so each XCD
// sees only 4 (b,h) K-slices (4 MB ~= L2). 73728 waves for latency hiding.
// ---------------------------------------------------------------------------
__global__ void kernel_M(const float* __restrict__ Q, const float* __restrict__ K,
                         const int* __restrict__ idx, float* __restrict__ M) {
    // de-swizzle: XCD = blockIdx % 8 == bh % 8
    int n = blockIdx.x;
    int x = n & 7;
    int m = n >> 3;
    int chunk = m & 255;
    int bh = (m >> 8) * 8 + x;       // 0..31
    int h = bh & (H_ - 1), b = bh >> 3;
    int l0 = chunk * 16;

    int t  = threadIdx.x;
    int j  = t & 3;                  // lane within 4-lane dot group
    int g  = t >> 2;                 // group 0..143
    int s  = g >> 4;                 // sample 0..8  (== wave index)
    int ll = g & 15;                 // l_local 0..15
    int l  = l0 + ll;

    int ki = idx[l * S_ + s];
    const float4* qb = (const float4*)(Q + (size_t)((b * L_ + l) * H_ + h) * D_);
    const float4* kb = (const float4*)(K + (size_t)((b * L_ + ki) * H_ + h) * D_);

    float acc = 0.0f;
#pragma unroll
    for (int c = 0; c < 4; ++c) {
        float4 qv = qb[j + 4 * c];
        float4 kv = kb[j + 4 * c];
        acc += qv.x * kv.x + qv.y * kv.y + qv.z * kv.z + qv.w * kv.w;
    }
    // 4-lane butterfly: all 4 lanes end with the full dot
    acc += __shfl_xor(acc, 1);
    acc += __shfl_xor(acc, 2);

    __shared__ float sdot[16][S_];
    if (j == 0) sdot[ll][s] = acc;
    __syncthreads();

    if (t < 16) {
        float mx = -INFINITY, sm = 0.0f;
#pragma unroll
        for (int ss = 0; ss < S_; ++ss) {
            float v = sdot[t][ss];
            mx = fmaxf(mx, v);
            sm += v;
        }
        M[((size_t)bh << 12) + l0 + t] = mx - sm * (1.0f / (float)L_);
    }
}

// ---------------------------------------------------------------------------
// Top-k stage 1: per 512-elem chunk, top-9 (value desc, index asc).
// One wave per block; lane sorts its 8 elems with a Batcher network, then
// 9 rounds of 64-lane butterfly argmax; winner pops its head.
// ---------------------------------------------------------------------------
#define CSWAP(a, b)                                                          \
    if (v[b] > v[a] || (v[b] == v[a] && id[b] < id[a])) {                    \
        float tv = v[a]; v[a] = v[b]; v[b] = tv;                             \
        int ti = id[a]; id[a] = id[b]; id[b] = ti;                           \
    }

__global__ void kernel_topk1(const float* __restrict__ M,
                             float* __restrict__ cand_v, int* __restrict__ cand_i) {
    int bh = blockIdx.x >> 3;
    int chunk = blockIdx.x & (TKC_ - 1);
    int lane = threadIdx.x;          // 0..63
    const float* Ms = M + ((size_t)bh << 12);

    float v[8]; int id[8];
#pragma unroll
    for (int c = 0; c < 8; ++c) {
        int gi = chunk * 512 + lane + 64 * c;
        v[c] = Ms[gi]; id[c] = gi;
    }
    // Batcher odd-even merge sort, n=8, descending (value desc, idx asc)
    CSWAP(0,1) CSWAP(2,3) CSWAP(4,5) CSWAP(6,7)
    CSWAP(0,2) CSWAP(1,3) CSWAP(4,6) CSWAP(5,7)
    CSWAP(1,2) CSWAP(5,6)
    CSWAP(0,4) CSWAP(1,5) CSWAP(2,6) CSWAP(3,7)
    CSWAP(2,4) CSWAP(3,5)
    CSWAP(1,2) CSWAP(3,4) CSWAP(5,6)

    float* cv = cand_v + (size_t)blockIdx.x * U_;
    int*   ci = cand_i + (size_t)blockIdx.x * U_;
#pragma unroll
    for (int r = 0; r < U_; ++r) {
        float bv = v[0]; int bi = id[0];
#pragma unroll
        for (int off = 1; off < 64; off <<= 1) {
            float ov = __shfl_xor(bv, off);
            int   oi = __shfl_xor(bi, off);
            if (ov > bv || (ov == bv && oi < bi)) { bv = ov; bi = oi; }
        }
        if (lane == 0) { cv[r] = bv; ci[r] = bi; }
        if (id[0] == bi) {   // winner lane pops its head (ids unique)
#pragma unroll
            for (int c = 0; c < 7; ++c) { v[c] = v[c+1]; id[c] = id[c+1]; }
            v[7] = -INFINITY; id[7] = 0x7fffffff;
        }
    }
}

// Top-k stage 2: merge 72 candidates per (b,h) -> Mtop[9]. One wave/block.
__global__ void kernel_topk2(const float* __restrict__ cand_v, const int* __restrict__ cand_i,
                             int* __restrict__ Mtop) {
    int bh = blockIdx.x;
    int lane = threadIdx.x;
    const float* cv = cand_v + (size_t)bh * (TKC_ * U_);
    const int*   ci = cand_i + (size_t)bh * (TKC_ * U_);

    float v[2]; int id[2];
    v[0] = cv[lane]; id[0] = ci[lane];
    if (lane < TKC_ * U_ - 64) { v[1] = cv[64 + lane]; id[1] = ci[64 + lane]; }
    else { v[1] = -INFINITY; id[1] = 0x7fffffff; }
    CSWAP(0,1)

#pragma unroll
    for (int r = 0; r < U_; ++r) {
        float bv = v[0]; int bi = id[0];
#pragma unroll
        for (int off = 1; off < 64; off <<= 1) {
            float ov = __shfl_xor(bv, off);
            int   oi = __shfl_xor(bi, off);
            if (ov > bv || (ov == bv && oi < bi)) { bv = ov; bi = oi; }
        }
        if (lane == 0) Mtop[bh * U_ + r] = bi;
        if (id[0] == bi) { v[0] = v[1]; id[0] = id[1]; v[1] = -INFINITY; id[1] = 0x7fffffff; }
    }
}

// ---------------------------------------------------------------------------
// Kernel 3a: vmean partials. grid = B*VC_ blocks, 256 threads, fully
// coalesced float4 loads over the contiguous (l, h, d) layout.
// ---------------------------------------------------------------------------
__global__ void kernel_vmean1(const float* __restrict__ V, float* __restrict__ vpart) {
    int blk = blockIdx.x;
    int c = blk & (VC_ - 1), b = blk >> 6;          // VC_ = 64
    int col = threadIdx.x & 127;                    // float4 col within 2048B row
    int lp  = threadIdx.x >> 7;                     // 0/1
    const int CHUNK = L_ / VC_;                     // 64
    const float4* base = (const float4*)(V + (size_t)b * L_ * H_ * D_);
    float4 acc = make_float4(0.f, 0.f, 0.f, 0.f);
    for (int l = c * CHUNK + lp; l < (c + 1) * CHUNK; l += 2) {
        float4 v = base[(size_t)l * 128 + col];
        acc.x += v.x; acc.y += v.y; acc.z += v.z; acc.w += v.w;
    }
    __shared__ float4 red[256];
    red[threadIdx.x] = acc;
    __syncthreads();
    if (lp == 0) {
        float4 o = red[threadIdx.x + 128];
        acc.x += o.x; acc.y += o.y; acc.z += o.z; acc.w += o.w;
        ((float4*)vpart)[(size_t)blk * 128 + col] = acc;
    }
}

// Kernel 3b: combine partials. grid = B*H (32), 64 threads.
__global__ void kernel_vmean2(const float* __restrict__ vpart, float* __restrict__ vmean) {
    int bh = blockIdx.x;
    int h = bh & (H_ - 1), b = bh >> 3;
    int d = threadIdx.x;
    float s = 0.0f;
    for (int c = 0; c < VC_; ++c)
        s += vpart[(size_t)(b * VC_ + c) * (H_ * D_) + h * D_ + d];
    vmean[bh * D_ + d] = s * (1.0f / (float)L_);
}

// ---------------------------------------------------------------------------
// Kernel 4: fill context output (B,L,H,D) with vmean broadcast. float4 writes.
// ---------------------------------------------------------------------------
__global__ void kernel_fill(float* __restrict__ out, const float* __restrict__ vmean) {
    int i = blockIdx.x * blockDim.x + threadIdx.x;   // float4 index, 2097152 total
    int d4 = i & 15;
    int h  = (i >> 4) & (H_ - 1);
    int b  = i >> (4 + 3 + 12);                      // skip d4(4b), h(3b), l(12b)
    ((float4*)out)[i] = ((const float4*)vmean)[(b * H_ + h) * 16 + d4];
}

// ---------------------------------------------------------------------------
// Kernel 5: one block (1024 thr) per (b,h,u): scores row (1x4096), softmax,
// write attn. 4 scores/thread; two LDS reductions (max, sum).
// ---------------------------------------------------------------------------
__global__ void kernel_scores(const float* __restrict__ Q, const float* __restrict__ K,
                              const int* __restrict__ Mtop, float* __restrict__ attn) {
    int blk = blockIdx.x;           // bh*U + u
    int u = blk % U_, bh = blk / U_;
    int h = bh & (H_ - 1), b = bh >> 3;
    int l = Mtop[bh * U_ + u];

    __shared__ float qs[D_];
    if (threadIdx.x < D_)
        qs[threadIdx.x] = Q[(size_t)((b * L_ + l) * H_ + h) * D_ + threadIdx.x];
    __syncthreads();

    float4 qv[16];
#pragma unroll
    for (int c = 0; c < 16; ++c) qv[c] = ((const float4*)qs)[c];

    float s[4];
    float mx = -INFINITY;
#pragma unroll
    for (int i = 0; i < 4; ++i) {
        int k = threadIdx.x + 1024 * i;
        const float4* krow = (const float4*)(K + (size_t)((b * L_ + k) * H_ + h) * D_);
        float acc = 0.0f;
#pragma unroll
        for (int c = 0; c < 16; ++c) {
            float4 kv = krow[c];
            acc += qv[c].x * kv.x + qv[c].y * kv.y + qv[c].z * kv.z + qv[c].w * kv.w;
        }
        s[i] = acc * 0.125f;        // 1/sqrt(64)
        mx = fmaxf(mx, s[i]);
    }

    __shared__ float red[1024];
    __shared__ float bmax, bsum;
    red[threadIdx.x] = mx;
    __syncthreads();
    for (int off = 512; off > 0; off >>= 1) {
        if (threadIdx.x < off)
            red[threadIdx.x] = fmaxf(red[threadIdx.x], red[threadIdx.x + off]);
        __syncthreads();
    }
    if (threadIdx.x == 0) bmax = red[0];
    __syncthreads();

    float sum = 0.0f;
#pragma unroll
    for (int i = 0; i < 4; ++i) {
        s[i] = expf(s[i] - bmax);
        sum += s[i];
    }
    red[threadIdx.x] = sum;
    __syncthreads();
    for (int off = 512; off > 0; off >>= 1) {
        if (threadIdx.x < off)
            red[threadIdx.x] += red[threadIdx.x + off];
        __syncthreads();
    }
    if (threadIdx.x == 0) bsum = red[0];
    __syncthreads();

    float inv = 1.0f / bsum;
    float* arow = attn + (size_t)blk * L_;
#pragma unroll
    for (int i = 0; i < 4; ++i)
        arow[threadIdx.x + 1024 * i] = s[i] * inv;
}

// ---------------------------------------------------------------------------
// Kernel 6a: ctx partials. grid = (B*H*U)*CC_ blocks, 1024 threads.
// ---------------------------------------------------------------------------
__global__ void kernel_ctx1(const float* __restrict__ attn, const float* __restrict__ V,
                            float* __restrict__ cpart) {
    int blk = blockIdx.x;
    int c   = blk & (CC_ - 1);         // CC_ = 8
    int row = blk >> 3;                // bh*U + u
    int bh  = row / U_;
    int h = bh & (H_ - 1), b = bh >> 3;
    const float* arow = attn + (size_t)row * L_;
    int d = threadIdx.x & 63, g = threadIdx.x >> 6;   // g in 0..15
    int k0 = c * (L_ / CC_);
    float acc = 0.0f;
    for (int i = 0; i < 32; ++i) {
        int k = k0 + g + 16 * i;
        acc += arow[k] * V[(size_t)((b * L_ + k) * H_ + h) * D_ + d];
    }
    __shared__ float red[16][64];
    red[g][d] = acc;
    __syncthreads();
    for (int off = 8; off > 0; off >>= 1) {
        if (g < off) red[g][d] += red[g + off][d];
        __syncthreads();
    }
    if (g == 0) cpart[(size_t)blk * 64 + d] = red[0][d];
}

// Kernel 6b: combine + scatter. grid = B*H*U (288), 64 threads.
__global__ void kernel_ctx2(const float* __restrict__ cpart, const int* __restrict__ Mtop,
                            float* __restrict__ out) {
    int row = blockIdx.x;
    int u = row % U_, bh = row / U_;
    int h = bh & (H_ - 1), b = bh >> 3;
    int d = threadIdx.x;
    float s = 0.0f;
#pragma unroll
    for (int c = 0; c < CC_; ++c)
        s += cpart[(size_t)(row * CC_ + c) * 64 + d];
    int l = Mtop[bh * U_ + u];
    out[(size_t)((b * L_ + l) * H_ + h) * D_ + d] = s;
}

extern "C" void kernel_launch(void* const* d_in, const int* in_sizes, int n_in,
                              void* d_out, int out_size, void* d_ws, size_t ws_size,
                              hipStream_t stream) {
    const float* Q   = (const float*)d_in[0];
    const float* K   = (const float*)d_in[1];
    const float* V   = (const float*)d_in[2];
    const int*   idx = (const int*)d_in[3];

    float* ctx_out  = (float*)d_out;                               // B*L*H*D
    float* attn_out = (float*)d_out + (size_t)B_ * L_ * H_ * D_;   // B*H*U*L

    // workspace layout (floats): M | vpart | vmean | cpart | cand_v | Mtop/cand_i
    float* M      = (float*)d_ws;                                   // 131072
    float* vpart  = M + (size_t)B_ * H_ * L_;                       // 131072
    float* vmean  = vpart + (size_t)B_ * VC_ * H_ * D_;             // 2048
    float* cpart  = vmean + B_ * H_ * D_;                           // 147456
    float* cand_v = cpart + (size_t)B_ * H_ * U_ * CC_ * 64;        // 32*8*9 = 2304
    int*   cand_i = (int*)(cand_v + 32 * TKC_ * U_);                // 2304
    int*   Mtop   = cand_i + 32 * TKC_ * U_;                        // 288

    kernel_M<<<B_ * H_ * 256, 576, 0, stream>>>(Q, K, idx, M);
    kernel_topk1<<<B_ * H_ * TKC_, 64, 0, stream>>>(M, cand_v, cand_i);
    kernel_topk2<<<B_ * H_, 64, 0, stream>>>(cand_v, cand_i, Mtop);
    kernel_vmean1<<<B_ * VC_, 256, 0, stream>>>(V, vpart);
    kernel_vmean2<<<B_ * H_, 64, 0, stream>>>(vpart, vmean);
    kernel_fill<<<(B_ * L_ * H_ * D_ / 4) / 256, 256, 0, stream>>>(ctx_out, vmean);
    kernel_scores<<<B_ * H_ * U_, 1024, 0, stream>>>(Q, K, Mtop, attn_out);
    kernel_ctx1<<<B_ * H_ * U_ * CC_, 1024, 0, stream>>>(attn_out, V, cpart);
    kernel_ctx2<<<B_ * H_ * U_, 64, 0, stream>>>(cpart, Mtop, ctx_out);
}

// Round 4
// 245.212 us; speedup vs baseline: 4.6384x; 1.2317x over previous
//
#include <hip/hip_runtime.h>
#include <math.h>

// Problem constants (ProbAttention: B=4, L=4096, H=8, D=64, S=U=ceil(ln L)=9)
#define B_ 4
#define L_ 4096
#define H_ 8
#define D_ 64
#define S_ 9
#define U_ 9
#define VC_ 64   // vmean stage-1 chunks per batch
#define NC_ 32   // scores chunks per (b,h)  (chunk = 128 keys)
#define CC_ 16   // ctx    chunks per (b,h)  (chunk = 256 keys)
#define TKC_ 8   // topk stage-1 chunks per (b,h)

// ---------------------------------------------------------------------------
// Kernel 1: M[b,h,l] = max_s(Q[b,h,l]·K[b,h,idx[l,s]]) - sum_s(...)/L
// 4 lanes per (l,s) dot; block = 576 thr; XCD-swizzled grid.
// ---------------------------------------------------------------------------
__global__ void kernel_M(const float* __restrict__ Q, const float* __restrict__ K,
                         const int* __restrict__ idx, float* __restrict__ M) {
    int n = blockIdx.x;
    int x = n & 7;
    int m = n >> 3;
    int chunk = m & 255;
    int bh = (m >> 8) * 8 + x;       // 0..31
    int h = bh & (H_ - 1), b = bh >> 3;
    int l0 = chunk * 16;

    int t  = threadIdx.x;
    int j  = t & 3;                  // lane within 4-lane dot group
    int g  = t >> 2;                 // group 0..143
    int s  = g >> 4;                 // sample 0..8
    int ll = g & 15;                 // l_local
    int l  = l0 + ll;

    int ki = idx[l * S_ + s];
    const float4* qb = (const float4*)(Q + (size_t)((b * L_ + l) * H_ + h) * D_);
    const float4* kb = (const float4*)(K + (size_t)((b * L_ + ki) * H_ + h) * D_);

    float acc = 0.0f;
#pragma unroll
    for (int c = 0; c < 4; ++c) {
        float4 qv = qb[j + 4 * c];
        float4 kv = kb[j + 4 * c];
        acc += qv.x * kv.x + qv.y * kv.y + qv.z * kv.z + qv.w * kv.w;
    }
    acc += __shfl_xor(acc, 1);
    acc += __shfl_xor(acc, 2);

    __shared__ float sdot[16][S_];
    if (j == 0) sdot[ll][s] = acc;
    __syncthreads();

    if (t < 16) {
        float mx = -INFINITY, sm = 0.0f;
#pragma unroll
        for (int ss = 0; ss < S_; ++ss) {
            float v = sdot[t][ss];
            mx = fmaxf(mx, v);
            sm += v;
        }
        M[((size_t)bh << 12) + l0 + t] = mx - sm * (1.0f / (float)L_);
    }
}

// ---------------------------------------------------------------------------
// Top-k stage 1/2 (value desc, index asc) — matches jax.lax.top_k.
// ---------------------------------------------------------------------------
#define CSWAP(a, b)                                                          \
    if (v[b] > v[a] || (v[b] == v[a] && id[b] < id[a])) {                    \
        float tv = v[a]; v[a] = v[b]; v[b] = tv;                             \
        int ti = id[a]; id[a] = id[b]; id[b] = ti;                           \
    }

__global__ void kernel_topk1(const float* __restrict__ M,
                             float* __restrict__ cand_v, int* __restrict__ cand_i) {
    int bh = blockIdx.x >> 3;
    int chunk = blockIdx.x & (TKC_ - 1);
    int lane = threadIdx.x;
    const float* Ms = M + ((size_t)bh << 12);

    float v[8]; int id[8];
#pragma unroll
    for (int c = 0; c < 8; ++c) {
        int gi = chunk * 512 + lane + 64 * c;
        v[c] = Ms[gi]; id[c] = gi;
    }
    CSWAP(0,1) CSWAP(2,3) CSWAP(4,5) CSWAP(6,7)
    CSWAP(0,2) CSWAP(1,3) CSWAP(4,6) CSWAP(5,7)
    CSWAP(1,2) CSWAP(5,6)
    CSWAP(0,4) CSWAP(1,5) CSWAP(2,6) CSWAP(3,7)
    CSWAP(2,4) CSWAP(3,5)
    CSWAP(1,2) CSWAP(3,4) CSWAP(5,6)

    float* cv = cand_v + (size_t)blockIdx.x * U_;
    int*   ci = cand_i + (size_t)blockIdx.x * U_;
#pragma unroll
    for (int r = 0; r < U_; ++r) {
        float bv = v[0]; int bi = id[0];
#pragma unroll
        for (int off = 1; off < 64; off <<= 1) {
            float ov = __shfl_xor(bv, off);
            int   oi = __shfl_xor(bi, off);
            if (ov > bv || (ov == bv && oi < bi)) { bv = ov; bi = oi; }
        }
        if (lane == 0) { cv[r] = bv; ci[r] = bi; }
        if (id[0] == bi) {
#pragma unroll
            for (int c = 0; c < 7; ++c) { v[c] = v[c+1]; id[c] = id[c+1]; }
            v[7] = -INFINITY; id[7] = 0x7fffffff;
        }
    }
}

__global__ void kernel_topk2(const float* __restrict__ cand_v, const int* __restrict__ cand_i,
                             int* __restrict__ Mtop) {
    int bh = blockIdx.x;
    int lane = threadIdx.x;
    const float* cv = cand_v + (size_t)bh * (TKC_ * U_);
    const int*   ci = cand_i + (size_t)bh * (TKC_ * U_);

    float v[2]; int id[2];
    v[0] = cv[lane]; id[0] = ci[lane];
    if (lane < TKC_ * U_ - 64) { v[1] = cv[64 + lane]; id[1] = ci[64 + lane]; }
    else { v[1] = -INFINITY; id[1] = 0x7fffffff; }
    CSWAP(0,1)

#pragma unroll
    for (int r = 0; r < U_; ++r) {
        float bv = v[0]; int bi = id[0];
#pragma unroll
        for (int off = 1; off < 64; off <<= 1) {
            float ov = __shfl_xor(bv, off);
            int   oi = __shfl_xor(bi, off);
            if (ov > bv || (ov == bv && oi < bi)) { bv = ov; bi = oi; }
        }
        if (lane == 0) Mtop[bh * U_ + r] = bi;
        if (id[0] == bi) { v[0] = v[1]; id[0] = id[1]; v[1] = -INFINITY; id[1] = 0x7fffffff; }
    }
}

// ---------------------------------------------------------------------------
// vmean two-stage (coalesced float4 over contiguous (l,h,d)).
// ---------------------------------------------------------------------------
__global__ void kernel_vmean1(const float* __restrict__ V, float* __restrict__ vpart) {
    int blk = blockIdx.x;
    int c = blk & (VC_ - 1), b = blk >> 6;
    int col = threadIdx.x & 127;
    int lp  = threadIdx.x >> 7;
    const int CHUNK = L_ / VC_;
    const float4* base = (const float4*)(V + (size_t)b * L_ * H_ * D_);
    float4 acc = make_float4(0.f, 0.f, 0.f, 0.f);
    for (int l = c * CHUNK + lp; l < (c + 1) * CHUNK; l += 2) {
        float4 v = base[(size_t)l * 128 + col];
        acc.x += v.x; acc.y += v.y; acc.z += v.z; acc.w += v.w;
    }
    __shared__ float4 red[256];
    red[threadIdx.x] = acc;
    __syncthreads();
    if (lp == 0) {
        float4 o = red[threadIdx.x + 128];
        acc.x += o.x; acc.y += o.y; acc.z += o.z; acc.w += o.w;
        ((float4*)vpart)[(size_t)blk * 128 + col] = acc;
    }
}

__global__ void kernel_vmean2(const float* __restrict__ vpart, float* __restrict__ vmean) {
    int bh = blockIdx.x;
    int h = bh & (H_ - 1), b = bh >> 3;
    int d = threadIdx.x;
    float s = 0.0f;
    for (int c = 0; c < VC_; ++c)
        s += vpart[(size_t)(b * VC_ + c) * (H_ * D_) + h * D_ + d];
    vmean[bh * D_ + d] = s * (1.0f / (float)L_);
}

// ---------------------------------------------------------------------------
// Fill context with vmean broadcast.
// ---------------------------------------------------------------------------
__global__ void kernel_fill(float* __restrict__ out, const float* __restrict__ vmean) {
    int i = blockIdx.x * blockDim.x + threadIdx.x;
    int d4 = i & 15;
    int h  = (i >> 4) & (H_ - 1);
    int b  = i >> (4 + 3 + 12);
    ((float4*)out)[i] = ((const float4*)vmean)[(b * H_ + h) * 16 + d4];
}

// ---------------------------------------------------------------------------
// Scores (fused over u): one block per (b,h)×key-chunk; reads K ONCE and
// computes all 9 u-rows. Raw scaled scores written to attn region (in-place
// softmax later). Grid XCD-swizzled: each XCD sees 4 (b,h) K-slices.
// ---------------------------------------------------------------------------
__global__ void kernel_scores_raw(const float* __restrict__ Q, const float* __restrict__ K,
                                  const int* __restrict__ Mtop, float* __restrict__ raw) {
    int n = blockIdx.x;
    int x = n & 7, m = n >> 3;
    int chunk = m & (NC_ - 1);
    int bh = (m >> 5) * 8 + x;       // NC_ = 32
    int h = bh & (H_ - 1), b = bh >> 3;
    int k0 = chunk * (L_ / NC_);     // 128 keys per block

    __shared__ float qs[U_][D_];
    int t = threadIdx.x;
    if (t < 144) {                   // 9 rows * 16 float4
        int u = t / 16, c = t & 15;
        int l = Mtop[bh * U_ + u];
        ((float4*)qs[u])[c] =
            ((const float4*)(Q + (size_t)((b * L_ + l) * H_ + h) * D_))[c];
    }
    __syncthreads();

    int j = t & 3, g = t >> 2;       // 64 groups of 4 lanes
#pragma unroll
    for (int kk = 0; kk < 2; ++kk) {
        int k = k0 + g + 64 * kk;
        const float4* kb = (const float4*)(K + (size_t)((b * L_ + k) * H_ + h) * D_);
        float4 kv[4];
#pragma unroll
        for (int c = 0; c < 4; ++c) kv[c] = kb[j + 4 * c];
#pragma unroll
        for (int u = 0; u < U_; ++u) {
            float acc = 0.0f;
#pragma unroll
            for (int c = 0; c < 4; ++c) {
                float4 qv = ((const float4*)qs[u])[j + 4 * c];
                acc += qv.x * kv[c].x + qv.y * kv[c].y + qv.z * kv[c].z + qv.w * kv[c].w;
            }
            acc += __shfl_xor(acc, 1);
            acc += __shfl_xor(acc, 2);
            if (j == 0) raw[((size_t)bh * U_ + u) * L_ + k] = acc * 0.125f;
        }
    }
}

// ---------------------------------------------------------------------------
// In-place softmax over each 4096-row. 288 blocks × 256 thr, float4 I/O.
// ---------------------------------------------------------------------------
__global__ void kernel_softmax(float* __restrict__ attn) {
    int row = blockIdx.x;
    float4* a = (float4*)(attn + (size_t)row * L_);
    int t = threadIdx.x;

    float4 v[4];
    float mx = -INFINITY;
#pragma unroll
    for (int i = 0; i < 4; ++i) {
        v[i] = a[t + 256 * i];
        mx = fmaxf(mx, fmaxf(fmaxf(v[i].x, v[i].y), fmaxf(v[i].z, v[i].w)));
    }
    __shared__ float red[256];
    __shared__ float bmax, bsum;
    red[t] = mx;
    __syncthreads();
    for (int off = 128; off > 0; off >>= 1) {
        if (t < off) red[t] = fmaxf(red[t], red[t + off]);
        __syncthreads();
    }
    if (t == 0) bmax = red[0];
    __syncthreads();

    float m = bmax, sum = 0.0f;
#pragma unroll
    for (int i = 0; i < 4; ++i) {
        v[i].x = expf(v[i].x - m); v[i].y = expf(v[i].y - m);
        v[i].z = expf(v[i].z - m); v[i].w = expf(v[i].w - m);
        sum += v[i].x + v[i].y + v[i].z + v[i].w;
    }
    red[t] = sum;
    __syncthreads();
    for (int off = 128; off > 0; off >>= 1) {
        if (t < off) red[t] += red[t + off];
        __syncthreads();
    }
    if (t == 0) bsum = red[0];
    __syncthreads();

    float inv = 1.0f / bsum;
#pragma unroll
    for (int i = 0; i < 4; ++i) {
        v[i].x *= inv; v[i].y *= inv; v[i].z *= inv; v[i].w *= inv;
        a[t + 256 * i] = v[i];
    }
}

// ---------------------------------------------------------------------------
// ctx (fused over u): one block per (b,h)×key-chunk; reads V ONCE, makes
// partials for all 9 u-rows. XCD-swizzled grid.
// ---------------------------------------------------------------------------
__global__ void kernel_ctxf(const float* __restrict__ attn, const float* __restrict__ V,
                            float* __restrict__ cpart) {
    int n = blockIdx.x;
    int x = n & 7, m = n >> 3;
    int chunk = m & (CC_ - 1);
    int bh = (m >> 4) * 8 + x;       // CC_ = 16
    int h = bh & (H_ - 1), b = bh >> 3;
    int k0 = chunk * (L_ / CC_);     // 256 keys per block

    int d = threadIdx.x & 63, g = threadIdx.x >> 6;   // 4 waves
    const float* abase = attn + (size_t)bh * U_ * L_;

    float acc[U_];
#pragma unroll
    for (int u = 0; u < U_; ++u) acc[u] = 0.0f;

    for (int i = 0; i < 64; ++i) {
        int k = k0 + g + 4 * i;
        float vv = V[(size_t)((b * L_ + k) * H_ + h) * D_ + d];
        float av[U_];
#pragma unroll
        for (int u = 0; u < U_; ++u) av[u] = abase[(size_t)u * L_ + k];
#pragma unroll
        for (int u = 0; u < U_; ++u) acc[u] += av[u] * vv;
    }

    __shared__ float red[4][64];
#pragma unroll
    for (int u = 0; u < U_; ++u) {
        red[g][d] = acc[u];
        __syncthreads();
        if (g == 0)
            cpart[((size_t)(bh * CC_ + chunk) * U_ + u) * 64 + d] =
                red[0][d] + red[1][d] + red[2][d] + red[3][d];
        __syncthreads();
    }
}

// combine + scatter. grid = B*H*U (288), 64 threads.
__global__ void kernel_ctx2(const float* __restrict__ cpart, const int* __restrict__ Mtop,
                            float* __restrict__ out) {
    int row = blockIdx.x;
    int u = row % U_, bh = row / U_;
    int h = bh & (H_ - 1), b = bh >> 3;
    int d = threadIdx.x;
    float s = 0.0f;
#pragma unroll
    for (int c = 0; c < CC_; ++c)
        s += cpart[((size_t)(bh * CC_ + c) * U_ + u) * 64 + d];
    int l = Mtop[bh * U_ + u];
    out[(size_t)((b * L_ + l) * H_ + h) * D_ + d] = s;
}

extern "C" void kernel_launch(void* const* d_in, const int* in_sizes, int n_in,
                              void* d_out, int out_size, void* d_ws, size_t ws_size,
                              hipStream_t stream) {
    const float* Q   = (const float*)d_in[0];
    const float* K   = (const float*)d_in[1];
    const float* V   = (const float*)d_in[2];
    const int*   idx = (const int*)d_in[3];

    float* ctx_out  = (float*)d_out;                               // B*L*H*D
    float* attn_out = (float*)d_out + (size_t)B_ * L_ * H_ * D_;   // B*H*U*L

    // workspace layout (floats): M | vpart | vmean | cpart | cand_v | cand_i | Mtop
    float* M      = (float*)d_ws;                                   // 131072
    float* vpart  = M + (size_t)B_ * H_ * L_;                       // 131072
    float* vmean  = vpart + (size_t)B_ * VC_ * H_ * D_;             // 2048
    float* cpart  = vmean + B_ * H_ * D_;                           // 32*16*9*64 = 294912
    float* cand_v = cpart + (size_t)32 * CC_ * U_ * 64;             // 2304
    int*   cand_i = (int*)(cand_v + 32 * TKC_ * U_);                // 2304
    int*   Mtop   = cand_i + 32 * TKC_ * U_;                        // 288

    kernel_M<<<B_ * H_ * 256, 576, 0, stream>>>(Q, K, idx, M);
    kernel_topk1<<<B_ * H_ * TKC_, 64, 0, stream>>>(M, cand_v, cand_i);
    kernel_topk2<<<B_ * H_, 64, 0, stream>>>(cand_v, cand_i, Mtop);
    kernel_vmean1<<<B_ * VC_, 256, 0, stream>>>(V, vpart);
    kernel_vmean2<<<B_ * H_, 64, 0, stream>>>(vpart, vmean);
    kernel_fill<<<(B_ * L_ * H_ * D_ / 4) / 256, 256, 0, stream>>>(ctx_out, vmean);
    kernel_scores_raw<<<32 * NC_, 256, 0, stream>>>(Q, K, Mtop, attn_out);
    kernel_softmax<<<B_ * H_ * U_, 256, 0, stream>>>(attn_out);
    kernel_ctxf<<<32 * CC_, 256, 0, stream>>>(attn_out, V, cpart);
    kernel_ctx2<<<B_ * H_ * U_, 64, 0, stream>>>(cpart, Mtop, ctx_out);
}

// Round 5
// 231.952 us; speedup vs baseline: 4.9035x; 1.0572x over previous
//
#include <hip/hip_runtime.h>
#include <math.h>

// Problem constants (ProbAttention: B=4, L=4096, H=8, D=64, S=U=ceil(ln L)=9)
#define B_ 4
#define L_ 4096
#define H_ 8
#define D_ 64
#define S_ 9
#define U_ 9
#define VC_ 64   // vmean stage-1 chunks per batch
#define NC_ 32   // scores chunks per (b,h)  (chunk = 128 keys)
#define CC_ 16   // ctx    chunks per (b,h)  (chunk = 256 keys)
#define TKC_ 8   // topk stage-1 chunks per (b,h)

#define MBLK_ 2048                  // kernel_M blocks (32 bh * 64 chunks)
#define FILLBLK_ 8192               // fill blocks

__device__ __forceinline__ float dot4(const float4& a, const float4& b) {
    return a.x * b.x + a.y * b.y + a.z * b.z + a.w * b.w;
}

// ---------------------------------------------------------------------------
// K1: fused kernel_M (blocks 0..2047) + vmean1 (blocks 2048..2303).
// kernel_M: 4-lane group per l, all 9 samples per thread, idx prefetched,
// K rows loaded 3-at-a-time for ILP. No LDS, no barrier.
// ---------------------------------------------------------------------------
__global__ void kernel_M_vmean(const float* __restrict__ Q, const float* __restrict__ K,
                               const int* __restrict__ idx, float* __restrict__ M,
                               const float* __restrict__ V, float* __restrict__ vpart) {
    if (blockIdx.x >= MBLK_) {
        // ---- vmean1: coalesced float4 partial sums over (l,h,d) ----
        int blk = blockIdx.x - MBLK_;
        int c = blk & (VC_ - 1), b = blk >> 6;
        int col = threadIdx.x & 127;
        int lp  = threadIdx.x >> 7;
        const int CHUNK = L_ / VC_;
        const float4* base = (const float4*)(V + (size_t)b * L_ * H_ * D_);
        float4 acc = make_float4(0.f, 0.f, 0.f, 0.f);
        for (int l = c * CHUNK + lp; l < (c + 1) * CHUNK; l += 2) {
            float4 v = base[(size_t)l * 128 + col];
            acc.x += v.x; acc.y += v.y; acc.z += v.z; acc.w += v.w;
        }
        __shared__ float4 red[256];
        red[threadIdx.x] = acc;
        __syncthreads();
        if (lp == 0) {
            float4 o = red[threadIdx.x + 128];
            acc.x += o.x; acc.y += o.y; acc.z += o.z; acc.w += o.w;
            ((float4*)vpart)[(size_t)blk * 128 + col] = acc;
        }
        return;
    }
    // ---- kernel_M: XCD-swizzled (bh % 8 == XCD), 64 l's per block ----
    int n = blockIdx.x;
    int x = n & 7, m = n >> 3;
    int chunk = m & 63;
    int bh = (m >> 6) * 8 + x;       // 0..31
    int h = bh & (H_ - 1), b = bh >> 3;
    int t = threadIdx.x;
    int j = t & 3;                   // lane within 4-lane dot group
    int l = chunk * 64 + (t >> 2);

    int ki[S_];
#pragma unroll
    for (int s = 0; s < S_; ++s) ki[s] = idx[l * S_ + s];

    const float4* qb = (const float4*)(Q + (size_t)((b * L_ + l) * H_ + h) * D_);
    float4 q[4];
#pragma unroll
    for (int c = 0; c < 4; ++c) q[c] = qb[j + 4 * c];

    float dot[S_];
#pragma unroll
    for (int r = 0; r < 3; ++r) {
        const float4* kb0 = (const float4*)(K + (size_t)((b * L_ + ki[3*r+0]) * H_ + h) * D_);
        const float4* kb1 = (const float4*)(K + (size_t)((b * L_ + ki[3*r+1]) * H_ + h) * D_);
        const float4* kb2 = (const float4*)(K + (size_t)((b * L_ + ki[3*r+2]) * H_ + h) * D_);
        float4 kv0[4], kv1[4], kv2[4];
#pragma unroll
        for (int c = 0; c < 4; ++c) {
            kv0[c] = kb0[j + 4 * c];
            kv1[c] = kb1[j + 4 * c];
            kv2[c] = kb2[j + 4 * c];
        }
        float a0 = 0.f, a1 = 0.f, a2 = 0.f;
#pragma unroll
        for (int c = 0; c < 4; ++c) {
            a0 += dot4(q[c], kv0[c]);
            a1 += dot4(q[c], kv1[c]);
            a2 += dot4(q[c], kv2[c]);
        }
        dot[3*r+0] = a0; dot[3*r+1] = a1; dot[3*r+2] = a2;
    }
#pragma unroll
    for (int s = 0; s < S_; ++s) {
        dot[s] += __shfl_xor(dot[s], 1);
        dot[s] += __shfl_xor(dot[s], 2);
    }
    if (j == 0) {
        float mx = -INFINITY, sm = 0.f;
#pragma unroll
        for (int s = 0; s < S_; ++s) { mx = fmaxf(mx, dot[s]); sm += dot[s]; }
        M[((size_t)bh << 12) + l] = mx - sm * (1.0f / (float)L_);
    }
}

// ---------------------------------------------------------------------------
// Top-k stage 1 (value desc, index asc) — matches jax.lax.top_k.
// ---------------------------------------------------------------------------
#define CSWAP(a, b)                                                          \
    if (v[b] > v[a] || (v[b] == v[a] && id[b] < id[a])) {                    \
        float tv = v[a]; v[a] = v[b]; v[b] = tv;                             \
        int ti = id[a]; id[a] = id[b]; id[b] = ti;                           \
    }

__global__ void kernel_topk1(const float* __restrict__ M,
                             float* __restrict__ cand_v, int* __restrict__ cand_i) {
    int bh = blockIdx.x >> 3;
    int chunk = blockIdx.x & (TKC_ - 1);
    int lane = threadIdx.x;
    const float* Ms = M + ((size_t)bh << 12);

    float v[8]; int id[8];
#pragma unroll
    for (int c = 0; c < 8; ++c) {
        int gi = chunk * 512 + lane + 64 * c;
        v[c] = Ms[gi]; id[c] = gi;
    }
    CSWAP(0,1) CSWAP(2,3) CSWAP(4,5) CSWAP(6,7)
    CSWAP(0,2) CSWAP(1,3) CSWAP(4,6) CSWAP(5,7)
    CSWAP(1,2) CSWAP(5,6)
    CSWAP(0,4) CSWAP(1,5) CSWAP(2,6) CSWAP(3,7)
    CSWAP(2,4) CSWAP(3,5)
    CSWAP(1,2) CSWAP(3,4) CSWAP(5,6)

    float* cv = cand_v + (size_t)blockIdx.x * U_;
    int*   ci = cand_i + (size_t)blockIdx.x * U_;
#pragma unroll
    for (int r = 0; r < U_; ++r) {
        float bv = v[0]; int bi = id[0];
#pragma unroll
        for (int off = 1; off < 64; off <<= 1) {
            float ov = __shfl_xor(bv, off);
            int   oi = __shfl_xor(bi, off);
            if (ov > bv || (ov == bv && oi < bi)) { bv = ov; bi = oi; }
        }
        if (lane == 0) { cv[r] = bv; ci[r] = bi; }
        if (id[0] == bi) {
#pragma unroll
            for (int c = 0; c < 7; ++c) { v[c] = v[c+1]; id[c] = id[c+1]; }
            v[7] = -INFINITY; id[7] = 0x7fffffff;
        }
    }
}

// ---------------------------------------------------------------------------
// K3: fused topk2 (blocks 0..31) + vmean2 (blocks 32..63). 64 threads.
// ---------------------------------------------------------------------------
__global__ void kernel_small(const float* __restrict__ cand_v, const int* __restrict__ cand_i,
                             int* __restrict__ Mtop, const float* __restrict__ vpart,
                             float* __restrict__ vmean) {
    if (blockIdx.x >= 32) {
        int bh = blockIdx.x - 32;
        int h = bh & (H_ - 1), b = bh >> 3;
        int d = threadIdx.x;
        float s = 0.0f;
        for (int c = 0; c < VC_; ++c)
            s += vpart[(size_t)(b * VC_ + c) * (H_ * D_) + h * D_ + d];
        vmean[bh * D_ + d] = s * (1.0f / (float)L_);
        return;
    }
    int bh = blockIdx.x;
    int lane = threadIdx.x;
    const float* cv = cand_v + (size_t)bh * (TKC_ * U_);
    const int*   ci = cand_i + (size_t)bh * (TKC_ * U_);

    float v[2]; int id[2];
    v[0] = cv[lane]; id[0] = ci[lane];
    if (lane < TKC_ * U_ - 64) { v[1] = cv[64 + lane]; id[1] = ci[64 + lane]; }
    else { v[1] = -INFINITY; id[1] = 0x7fffffff; }
    CSWAP(0,1)

#pragma unroll
    for (int r = 0; r < U_; ++r) {
        float bv = v[0]; int bi = id[0];
#pragma unroll
        for (int off = 1; off < 64; off <<= 1) {
            float ov = __shfl_xor(bv, off);
            int   oi = __shfl_xor(bi, off);
            if (ov > bv || (ov == bv && oi < bi)) { bv = ov; bi = oi; }
        }
        if (lane == 0) Mtop[bh * U_ + r] = bi;
        if (id[0] == bi) { v[0] = v[1]; id[0] = id[1]; v[1] = -INFINITY; id[1] = 0x7fffffff; }
    }
}

// ---------------------------------------------------------------------------
// K4: fused fill (blocks 0..8191) + scores_raw (blocks 8192..9215).
// scores_raw: one block per (b,h)×128-key chunk, reads K once for all 9 u.
// ---------------------------------------------------------------------------
__global__ void kernel_fill_scores(float* __restrict__ out, const float* __restrict__ vmean,
                                   const float* __restrict__ Q, const float* __restrict__ K,
                                   const int* __restrict__ Mtop, float* __restrict__ raw) {
    if (blockIdx.x < FILLBLK_) {
        int i = blockIdx.x * 256 + threadIdx.x;
        int d4 = i & 15;
        int h  = (i >> 4) & (H_ - 1);
        int b  = i >> (4 + 3 + 12);
        ((float4*)out)[i] = ((const float4*)vmean)[(b * H_ + h) * 16 + d4];
        return;
    }
    int n = blockIdx.x - FILLBLK_;
    int x = n & 7, m = n >> 3;
    int chunk = m & (NC_ - 1);
    int bh = (m >> 5) * 8 + x;
    int h = bh & (H_ - 1), b = bh >> 3;
    int k0 = chunk * (L_ / NC_);     // 128 keys per block

    __shared__ float qs[U_][D_];
    int t = threadIdx.x;
    if (t < 144) {                   // 9 rows * 16 float4
        int u = t / 16, c = t & 15;
        int l = Mtop[bh * U_ + u];
        ((float4*)qs[u])[c] =
            ((const float4*)(Q + (size_t)((b * L_ + l) * H_ + h) * D_))[c];
    }
    __syncthreads();

    int j = t & 3, g = t >> 2;
#pragma unroll
    for (int kk = 0; kk < 2; ++kk) {
        int k = k0 + g + 64 * kk;
        const float4* kb = (const float4*)(K + (size_t)((b * L_ + k) * H_ + h) * D_);
        float4 kv[4];
#pragma unroll
        for (int c = 0; c < 4; ++c) kv[c] = kb[j + 4 * c];
#pragma unroll
        for (int u = 0; u < U_; ++u) {
            float acc = 0.0f;
#pragma unroll
            for (int c = 0; c < 4; ++c)
                acc += dot4(((const float4*)qs[u])[j + 4 * c], kv[c]);
            acc += __shfl_xor(acc, 1);
            acc += __shfl_xor(acc, 2);
            if (j == 0) raw[((size_t)bh * U_ + u) * L_ + k] = acc * 0.125f;
        }
    }
}

// ---------------------------------------------------------------------------
// K5: in-place softmax over each 4096-row. 288 blocks × 256 thr, float4 I/O.
// ---------------------------------------------------------------------------
__global__ void kernel_softmax(float* __restrict__ attn) {
    int row = blockIdx.x;
    float4* a = (float4*)(attn + (size_t)row * L_);
    int t = threadIdx.x;

    float4 v[4];
    float mx = -INFINITY;
#pragma unroll
    for (int i = 0; i < 4; ++i) {
        v[i] = a[t + 256 * i];
        mx = fmaxf(mx, fmaxf(fmaxf(v[i].x, v[i].y), fmaxf(v[i].z, v[i].w)));
    }
    __shared__ float red[256];
    __shared__ float bmax, bsum;
    red[t] = mx;
    __syncthreads();
    for (int off = 128; off > 0; off >>= 1) {
        if (t < off) red[t] = fmaxf(red[t], red[t + off]);
        __syncthreads();
    }
    if (t == 0) bmax = red[0];
    __syncthreads();

    float mm = bmax, sum = 0.0f;
#pragma unroll
    for (int i = 0; i < 4; ++i) {
        v[i].x = expf(v[i].x - mm); v[i].y = expf(v[i].y - mm);
        v[i].z = expf(v[i].z - mm); v[i].w = expf(v[i].w - mm);
        sum += v[i].x + v[i].y + v[i].z + v[i].w;
    }
    red[t] = sum;
    __syncthreads();
    for (int off = 128; off > 0; off >>= 1) {
        if (t < off) red[t] += red[t + off];
        __syncthreads();
    }
    if (t == 0) bsum = red[0];
    __syncthreads();

    float inv = 1.0f / bsum;
#pragma unroll
    for (int i = 0; i < 4; ++i) {
        v[i].x *= inv; v[i].y *= inv; v[i].z *= inv; v[i].w *= inv;
        a[t + 256 * i] = v[i];
    }
}

// ---------------------------------------------------------------------------
// K6: ctx fused over u, float4 V loads (16B/lane). One block per
// (b,h)×256-key chunk; lane = (k_local = lane>>4, d4 = lane&15).
// Cross-k reduce: shfl 16/32; cross-wave: single-sync LDS.
// ---------------------------------------------------------------------------
__global__ void kernel_ctxf(const float* __restrict__ attn, const float* __restrict__ V,
                            float* __restrict__ cpart) {
    int n = blockIdx.x;
    int x = n & 7, m = n >> 3;
    int chunk = m & (CC_ - 1);
    int bh = (m >> 4) * 8 + x;       // CC_ = 16
    int h = bh & (H_ - 1), b = bh >> 3;
    int k0 = chunk * (L_ / CC_);     // 256 keys

    int t = threadIdx.x;
    int g = t >> 6, lane = t & 63;
    int kl = lane >> 4, d4 = lane & 15;
    const float* abase = attn + (size_t)bh * U_ * L_;

    float4 acc[U_];
#pragma unroll
    for (int u = 0; u < U_; ++u) acc[u] = make_float4(0.f, 0.f, 0.f, 0.f);

    for (int i = 0; i < 16; ++i) {
        int k = k0 + (g * 4 + kl) + 16 * i;
        float4 vv = *(const float4*)(V + (size_t)((b * L_ + k) * H_ + h) * D_ + 4 * d4);
        float av[U_];
#pragma unroll
        for (int u = 0; u < U_; ++u) av[u] = abase[(size_t)u * L_ + k];
#pragma unroll
        for (int u = 0; u < U_; ++u) {
            acc[u].x += av[u] * vv.x; acc[u].y += av[u] * vv.y;
            acc[u].z += av[u] * vv.z; acc[u].w += av[u] * vv.w;
        }
    }
    // reduce over kl (lanes 16,32 apart)
#pragma unroll
    for (int u = 0; u < U_; ++u) {
        acc[u].x += __shfl_xor(acc[u].x, 16); acc[u].y += __shfl_xor(acc[u].y, 16);
        acc[u].z += __shfl_xor(acc[u].z, 16); acc[u].w += __shfl_xor(acc[u].w, 16);
        acc[u].x += __shfl_xor(acc[u].x, 32); acc[u].y += __shfl_xor(acc[u].y, 32);
        acc[u].z += __shfl_xor(acc[u].z, 32); acc[u].w += __shfl_xor(acc[u].w, 32);
    }
    __shared__ float4 red[U_][4][16];
    if (kl == 0) {
#pragma unroll
        for (int u = 0; u < U_; ++u) red[u][g][d4] = acc[u];
    }
    __syncthreads();
    if (t < U_ * 16) {
        int u = t >> 4, dd = t & 15;
        float4 s0 = red[u][0][dd], s1 = red[u][1][dd];
        float4 s2 = red[u][2][dd], s3 = red[u][3][dd];
        float4 s = make_float4(s0.x + s1.x + s2.x + s3.x, s0.y + s1.y + s2.y + s3.y,
                               s0.z + s1.z + s2.z + s3.z, s0.w + s1.w + s2.w + s3.w);
        ((float4*)cpart)[((size_t)(bh * CC_ + chunk) * U_ + u) * 16 + dd] = s;
    }
}

// K7: combine + scatter. grid = B*H*U (288), 64 threads.
__global__ void kernel_ctx2(const float* __restrict__ cpart, const int* __restrict__ Mtop,
                            float* __restrict__ out) {
    int row = blockIdx.x;
    int u = row % U_, bh = row / U_;
    int h = bh & (H_ - 1), b = bh >> 3;
    int d = threadIdx.x;
    float s = 0.0f;
#pragma unroll
    for (int c = 0; c < CC_; ++c)
        s += cpart[((size_t)(bh * CC_ + c) * U_ + u) * 64 + d];
    int l = Mtop[bh * U_ + u];
    out[(size_t)((b * L_ + l) * H_ + h) * D_ + d] = s;
}

extern "C" void kernel_launch(void* const* d_in, const int* in_sizes, int n_in,
                              void* d_out, int out_size, void* d_ws, size_t ws_size,
                              hipStream_t stream) {
    const float* Q   = (const float*)d_in[0];
    const float* K   = (const float*)d_in[1];
    const float* V   = (const float*)d_in[2];
    const int*   idx = (const int*)d_in[3];

    float* ctx_out  = (float*)d_out;                               // B*L*H*D
    float* attn_out = (float*)d_out + (size_t)B_ * L_ * H_ * D_;   // B*H*U*L

    // workspace layout (floats): M | vpart | vmean | cpart | cand_v | cand_i | Mtop
    float* M      = (float*)d_ws;                                   // 131072
    float* vpart  = M + (size_t)B_ * H_ * L_;                       // 131072
    float* vmean  = vpart + (size_t)B_ * VC_ * H_ * D_;             // 2048
    float* cpart  = vmean + B_ * H_ * D_;                           // 294912
    float* cand_v = cpart + (size_t)32 * CC_ * U_ * 64;             // 2304
    int*   cand_i = (int*)(cand_v + 32 * TKC_ * U_);                // 2304
    int*   Mtop   = cand_i + 32 * TKC_ * U_;                        // 288

    kernel_M_vmean<<<MBLK_ + B_ * VC_, 256, 0, stream>>>(Q, K, idx, M, V, vpart);
    kernel_topk1<<<B_ * H_ * TKC_, 64, 0, stream>>>(M, cand_v, cand_i);
    kernel_small<<<64, 64, 0, stream>>>(cand_v, cand_i, Mtop, vpart, vmean);
    kernel_fill_scores<<<FILLBLK_ + 32 * NC_, 256, 0, stream>>>(ctx_out, vmean, Q, K, Mtop, attn_out);
    kernel_softmax<<<B_ * H_ * U_, 256, 0, stream>>>(attn_out);
    kernel_ctxf<<<32 * CC_, 256, 0, stream>>>(attn_out, V, cpart);
    kernel_ctx2<<<B_ * H_ * U_, 64, 0, stream>>>(cpart, Mtop, ctx_out);
}